// Round 11
// baseline (91.590 us; speedup 1.0000x reference)
//
#include <hip/hip_runtime.h>
#include <hip/hip_bf16.h>
#include <math.h>

#define NN 4096
#define FIN 512
#define HH 8
#define DD 64

typedef unsigned long long u64;
typedef unsigned int u32;
typedef float f32x2 __attribute__((ext_vector_type(2)));
typedef float f32x4 __attribute__((ext_vector_type(4)));
typedef float f32x16 __attribute__((ext_vector_type(16)));
typedef short short8 __attribute__((ext_vector_type(8)));

#define GLOAD_LDS16(g, l)                                                              \
  __builtin_amdgcn_global_load_lds((const __attribute__((address_space(1))) u32*)(g),  \
                                   (__attribute__((address_space(3))) u32*)(l), 16, 0, 0)

#if __has_builtin(__builtin_amdgcn_exp2f)
#define EXP2F(x) __builtin_amdgcn_exp2f(x)
#else
#define EXP2F(x) exp2f(x)
#endif

__device__ inline ushort bf16rne(float f) {
    u32 u = __float_as_uint(f);
    u += 0x7FFFu + ((u >> 16) & 1u);
    return (ushort)(u >> 16);
}
__device__ inline float bf16tof(ushort h) {
    return __uint_as_float(((u32)h) << 16);
}

// weight pair: z = s+t; lrelu; exp2; mask; lacc; pack to bf16x2 via v_cvt_pk
__device__ inline u32 wpair(float sv, f32x2 t2, u32 msk, int q, f32x2& lac) {
    f32x2 z; z[0] = sv + t2[0]; z[1] = sv + t2[1];
    f32x2 zl = z * 0.2f;
    float z0 = fmaxf(z[0], zl[0]);
    float z1 = fmaxf(z[1], zl[1]);
    float e0 = EXP2F(z0), e1 = EXP2F(z1);
    e0 = ((msk >> (2 * q)) & 1u) ? e0 : 0.f;
    e1 = ((msk >> (2 * q + 1)) & 1u) ? e1 : 0.f;
    f32x2 ev; ev[0] = e0; ev[1] = e1;
    lac += ev;
    u32 d;
    asm("v_cvt_pk_bf16_f32 %0, %1, %2" : "=v"(d) : "v"(e0), "v"(e1));
    return d;
}

// ---------- Kernel 1: merged prep: bitpack adj (transposed) | split x | W tiles ----------
__global__ __launch_bounds__(256) void k_prep(const int* __restrict__ adj,
                                              const float* __restrict__ x,
                                              const float* __restrict__ W,
                                              u64* __restrict__ bmT,
                                              ushort* __restrict__ xh,
                                              ushort* __restrict__ xl,
                                              ushort* __restrict__ WTs) {
    int b = blockIdx.x;
    if (b < 65536) {
        int tid = b * 256 + threadIdx.x;
        int lane = threadIdx.x & 63;
        int v = adj[tid];
        u64 m = __ballot(v > 0);
        if (lane == 0) {
            int i = tid >> 12;           // row
            int j = tid & 4095;          // col of this wave's first lane
            bmT[(size_t)(j >> 6) * NN + i] = m;   // transposed: [jword][i]
        }
    } else if (b < 65536 + 2048) {
        int tid = (b - 65536) * 256 + threadIdx.x;     // NN*FIN/4 threads
        float4 v = *(const float4*)(x + (size_t)tid * 4);
        float fa[4] = {v.x, v.y, v.z, v.w};
        ushort4 hh, ll;
        ushort* hp = (ushort*)&hh; ushort* lp = (ushort*)&ll;
        #pragma unroll
        for (int k = 0; k < 4; ++k) {
            ushort hv = bf16rne(fa[k]);
            hp[k] = hv;
            lp[k] = bf16rne(fa[k] - bf16tof(hv));
        }
        *(ushort4*)(xh + (size_t)tid * 4) = hh;
        *(ushort4*)(xl + (size_t)tid * 4) = ll;
    } else {
        int gid = (b - 67584) * 256 + threadIdx.x;     // 32768 threads
        int d = gid & 63, kg = (gid >> 6) & 7, kt = (gid >> 9) & 7, h = gid >> 12;
        ushort hh[8], ll[8];
        #pragma unroll
        for (int e = 0; e < 8; ++e) {
            int f = kt * 64 + kg * 8 + e;
            float wv = W[((size_t)h * FIN + f) * DD + d];
            ushort hv = bf16rne(wv);
            hh[e] = hv;
            ll[e] = bf16rne(wv - bf16tof(hv));
        }
        *(uint4*)(WTs + ((size_t)((h * 2 + 0) * 8 + kt)) * 4096 + d * 64 + kg * 8) = *(uint4*)hh;
        *(uint4*)(WTs + ((size_t)((h * 2 + 1) * 8 + kt)) * 4096 + d * 64 + kg * 8) = *(uint4*)ll;
    }
}

// ---------- Kernel 2: MFMA projection, LDS-staged, 16 waves/block ----------
// grid (NN/64, HH), 1024 thr. Outputs WhbT linear tiles [h][it][d(64)][j(64)] bf16;
// s, t32 (both f32, pre-scaled by log2e).
__global__ __launch_bounds__(1024) void k_proj(const ushort* __restrict__ xh,
                                               const ushort* __restrict__ xl,
                                               const ushort* __restrict__ WTs,
                                               const float* __restrict__ a_src,
                                               const float* __restrict__ a_dst,
                                               ushort* __restrict__ WhbT,
                                               float* __restrict__ s,
                                               float* __restrict__ t32) {
    __shared__ ushort P[16384];        // 4 bufs (Ah,Al,Bh,Bl) x 8KB, swizzled image
    __shared__ float SP[64][5], TP[64][5];
    int h = blockIdx.y, it = blockIdx.x;
    int i0 = it * 64;
    int tid = threadIdx.x;
    int w = tid >> 6, lane = tid & 63, lm = lane & 15, g = lane >> 4;
    int w_c = w & 3, w_i = w >> 2;
    f32x4 acc = {};
    int da = w_c * 16 + lm, ib = w_i * 16 + lm;
    for (int kt = 0; kt < 8; ++kt) {
        #pragma unroll
        for (int sub = 0; sub < 2; ++sub) {
            int buf = sub * 2 + (w >> 3);          // wave-uniform
            int y0 = (w & 7) * 64;                 // wave-uniform chunk base
            int y = y0 + lane;
            int r = y >> 3;
            int cc = (y & 7) ^ (r & 7);            // sigma: inverse-swizzle source
            const ushort* src;
            if (buf == 0)      src = WTs + ((size_t)((h * 2 + 0) * 8 + kt)) * 4096 + r * 64 + cc * 8;
            else if (buf == 1) src = WTs + ((size_t)((h * 2 + 1) * 8 + kt)) * 4096 + r * 64 + cc * 8;
            else if (buf == 2) src = xh + (size_t)(i0 + r) * FIN + kt * 64 + cc * 8;
            else               src = xl + (size_t)(i0 + r) * FIN + kt * 64 + cc * 8;
            GLOAD_LDS16(src, P + buf * 4096 + y0 * 8);
        }
        __syncthreads();
        #pragma unroll
        for (int ks = 0; ks < 2; ++ks) {
            u32 offA = ((u32)(da * 128 + ks * 64 + g * 16)) ^ ((u32)(da & 7) << 4);
            u32 offB = ((u32)(ib * 128 + ks * 64 + g * 16)) ^ ((u32)(ib & 7) << 4);
            short8 ah = *(const short8*)((const char*)P + offA);
            short8 al = *(const short8*)((const char*)P + 8192 + offA);
            short8 bh = *(const short8*)((const char*)P + 16384 + offB);
            short8 bl = *(const short8*)((const char*)P + 24576 + offB);
            acc = __builtin_amdgcn_mfma_f32_16x16x32_bf16(ah, bh, acc, 0, 0, 0);
            acc = __builtin_amdgcn_mfma_f32_16x16x32_bf16(al, bh, acc, 0, 0, 0);
            acc = __builtin_amdgcn_mfma_f32_16x16x32_bf16(ah, bl, acc, 0, 0, 0);
        }
        __syncthreads();
    }
    // epilogue: s,t partials + C tile. C[row=d=w_c*16+g*4+reg][col=i=w_i*16+lm]
    float4 as4 = *(const float4*)(a_src + h * DD + w_c * 16 + g * 4);
    float4 ad4 = *(const float4*)(a_dst + h * DD + w_c * 16 + g * 4);
    float sp = acc[0] * as4.x + acc[1] * as4.y + acc[2] * as4.z + acc[3] * as4.w;
    float tp = acc[0] * ad4.x + acc[1] * ad4.y + acc[2] * ad4.z + acc[3] * ad4.w;
    sp += __shfl_xor(sp, 16); sp += __shfl_xor(sp, 32);
    tp += __shfl_xor(tp, 16); tp += __shfl_xor(tp, 32);
    if (lane < 16) { SP[w_i * 16 + lm][w_c] = sp; TP[w_i * 16 + lm][w_c] = tp; }
    #pragma unroll
    for (int reg = 0; reg < 4; ++reg) {
        int d = w_c * 16 + g * 4 + reg;
        P[d * 64 + w_i * 16 + lm] = bf16rne(acc[reg]);
    }
    __syncthreads();
    const float LOG2E = 1.4426950408889634f;
    if (tid < 64) {
        int i = i0 + tid;
        s[h * NN + i]   = (SP[tid][0] + SP[tid][1] + SP[tid][2] + SP[tid][3]) * LOG2E;
        t32[h * NN + i] = (TP[tid][0] + TP[tid][1] + TP[tid][2] + TP[tid][3]) * LOG2E;
    }
    ushort* tbase = WhbT + ((size_t)(h * 64 + it)) * 4096;
    if (tid < 512) {
        uint4 v = *(const uint4*)(P + tid * 8);
        *(uint4*)(tbase + tid * 8) = v;
    }
}

// ---------- Kernel 3: wave-autonomous fused aggregation (counted-vmcnt pipeline) ----------
// grid (NN/64, HH), 512 thr = 8 waves. Wave w owns j-slice [w*512,(w+1)*512),
// covers ALL 64 rows (2 A-frags, 4 accs); wave-private 16KB V dbuf; NO barriers
// in the K-loop (self-sync via counted s_waitcnt vmcnt). In-LDS 8-way combine.
__global__ __launch_bounds__(512, 2) void k_agg(const ushort* __restrict__ WhbT,
                                                const float* __restrict__ s,
                                                const float* __restrict__ t32,
                                                const u64* __restrict__ bmT,
                                                float* __restrict__ out) {
    __shared__ __attribute__((aligned(16))) char SM[149504];
    float* tls = (float*)(SM + 131072);        // 16KB f32 t (log2-scaled)
    float* PL  = (float*)(SM + 147456);        // 8 waves x 64 rows l-partials
    int h = blockIdx.y;
    int i0 = blockIdx.x * 64;
    int tid = threadIdx.x;
    int w = tid >> 6, lane = tid & 63, r = lane & 31, hi = lane >> 5;
    int irow0 = i0 + r, irow1 = i0 + 32 + r;
    float s0 = s[(size_t)h * NN + irow0];      // log2-scaled
    float s1 = s[(size_t)h * NN + irow1];
    char* Vtw = SM + w * 16384;                // wave-private dbuf (2 x 8KB)
    int jt0 = w * 8;
    const ushort* tb0 = WhbT + ((size_t)(h * 64 + jt0)) * 4096;
    int slane8 = (lane ^ ((lane >> 3) & 7)) * 8;   // sigma-permuted source, lane part

    auto stage = [&](int p, int k) {
        const ushort* tb = tb0 + (size_t)k * 4096;
        #pragma unroll
        for (int q = 0; q < 8; ++q)
            GLOAD_LDS16(tb + q * 512 + slane8, Vtw + p * 8192 + q * 1024);
    };
    stage(0, 0);
    // preload ALL mask words (keeps loop vmem = exactly the 8 stage loads)
    u64 bits0[8], bits1[8];
    #pragma unroll
    for (int k = 0; k < 8; ++k) {
        bits0[k] = bmT[(size_t)(jt0 + k) * NN + irow0];
        bits1[k] = bmT[(size_t)(jt0 + k) * NN + irow1];
    }
    // stage t once (16KB, whole block)
    {
        const float4* src = (const float4*)(t32 + (size_t)h * NN) + tid * 2;
        ((float4*)tls)[tid * 2]     = src[0];
        ((float4*)tls)[tid * 2 + 1] = src[1];
    }
    __syncthreads();   // t visible; drains tile-0 + bits loads (once)

    f32x16 a00 = {}, a01 = {}, a10 = {}, a11 = {};
    f32x2 l0 = {}, l1 = {};
    u32 swz = ((u32)(r & 7)) << 4;
    const char* Vr = Vtw + r * 128;
    #pragma unroll
    for (int k = 0; k < 8; ++k) {
        if (k < 7) {
            stage((k + 1) & 1, k + 1);
            asm volatile("s_waitcnt vmcnt(8)" ::: "memory");   // tile k landed; k+1 in flight
        } else {
            asm volatile("s_waitcnt vmcnt(0)" ::: "memory");
        }
        __builtin_amdgcn_sched_barrier(0);
        const float* tb_t = tls + (jt0 + k) * 64;
        u32 w0lo = (u32)(bits0[k] >> (hi * 8)), w0hi = (u32)(bits0[k] >> (32 + hi * 8));
        u32 w1lo = (u32)(bits1[k] >> (hi * 8)), w1hi = (u32)(bits1[k] >> (32 + hi * 8));
        u32 mb0[4] = {w0lo & 0xffu, (w0lo >> 16) & 0xffu, w0hi & 0xffu, (w0hi >> 16) & 0xffu};
        u32 mb1[4] = {w1lo & 0xffu, (w1lo >> 16) & 0xffu, w1hi & 0xffu, (w1hi >> 16) & 0xffu};
        const char* Vp = Vr + (k & 1) * 8192;
        #pragma unroll
        for (int jq = 0; jq < 4; ++jq) {
            float ta[8];
            *(f32x4*)&ta[0] = *(const f32x4*)(tb_t + jq * 16 + hi * 8);
            *(f32x4*)&ta[4] = *(const f32x4*)(tb_t + jq * 16 + hi * 8 + 4);
            union { u32 u[4]; short8 v8; } A0, A1;
            #pragma unroll
            for (int q = 0; q < 4; ++q) {
                f32x2 t2; t2[0] = ta[2 * q]; t2[1] = ta[2 * q + 1];
                A0.u[q] = wpair(s0, t2, mb0[jq], q, l0);
                A1.u[q] = wpair(s1, t2, mb1[jq], q, l1);
            }
            u32 co = ((u32)(jq * 32 + hi * 16)) ^ swz;
            short8 b0 = *(const short8*)(Vp + co);            // d 0..31 (row r)
            short8 b1 = *(const short8*)(Vp + co + 4096);     // d 32..63
            __builtin_amdgcn_s_setprio(1);
            a00 = __builtin_amdgcn_mfma_f32_32x32x16_bf16(A0.v8, b0, a00, 0, 0, 0);
            a01 = __builtin_amdgcn_mfma_f32_32x32x16_bf16(A0.v8, b1, a01, 0, 0, 0);
            a10 = __builtin_amdgcn_mfma_f32_32x32x16_bf16(A1.v8, b0, a10, 0, 0, 0);
            a11 = __builtin_amdgcn_mfma_f32_32x32x16_bf16(A1.v8, b1, a11, 0, 0, 0);
            __builtin_amdgcn_s_setprio(0);
        }
    }
    // ---- combine: wave writes its 64x64 partial into its own (dead) Vt area ----
    float l0s = l0[0] + l0[1];
    float l1s = l1[0] + l1[1];
    l0s += __shfl_xor(l0s, 32);
    l1s += __shfl_xor(l1s, 32);
    float* PTw = (float*)Vtw;                  // [64 rows][64 d] f32 = 16KB
    #pragma unroll
    for (int reg = 0; reg < 16; ++reg) {
        int rowl = (reg & 3) + 8 * (reg >> 2) + 4 * hi;
        PTw[rowl * 64 + r]             = a00[reg];
        PTw[rowl * 64 + 32 + r]        = a01[reg];
        PTw[(32 + rowl) * 64 + r]      = a10[reg];
        PTw[(32 + rowl) * 64 + 32 + r] = a11[reg];
    }
    if (lane < 32) {
        PL[w * 64 + r]      = l0s;
        PL[w * 64 + 32 + r] = l1s;
    }
    __syncthreads();
    // epilogue: tid -> row (0..63), d0 = 8-float group; 8-way reduce, ELU, store
    int row = tid >> 3, d0 = (tid & 7) * 8;
    f32x4 A0 = {}, A1 = {};
    float l = 0.f;
    #pragma unroll
    for (int gg = 0; gg < 8; ++gg) {
        const float* Pp = (const float*)(SM + gg * 16384) + row * 64 + d0;
        A0 += *(const f32x4*)Pp;
        A1 += *(const f32x4*)(Pp + 4);
        l += PL[gg * 64 + row];
    }
    float inv = 1.f / l;
    float o[8];
    #pragma unroll
    for (int dd = 0; dd < 4; ++dd) {
        float u0 = A0[dd] * inv;
        float u1 = A1[dd] * inv;
        o[dd]     = u0 > 0.f ? u0 : __expf(u0) - 1.f;
        o[dd + 4] = u1 > 0.f ? u1 : __expf(u1) - 1.f;
    }
    float* ob = out + (size_t)(i0 + row) * (HH * DD) + h * DD + d0;
    *(float4*)ob       = make_float4(o[0], o[1], o[2], o[3]);
    *(float4*)(ob + 4) = make_float4(o[4], o[5], o[6], o[7]);
}

extern "C" void kernel_launch(void* const* d_in, const int* in_sizes, int n_in,
                              void* d_out, int out_size, void* d_ws, size_t ws_size,
                              hipStream_t stream) {
    const float* x     = (const float*)d_in[0];
    const int*   adj   = (const int*)d_in[1];
    const float* W     = (const float*)d_in[2];
    const float* a_src = (const float*)d_in[3];
    const float* a_dst = (const float*)d_in[4];
    float* out = (float*)d_out;

    char* ws = (char*)d_ws;
    const size_t MB = 1024 * 1024;
    ushort* WhbT = (ushort*)ws;                          // 4 MB, linear tiles
    u64*    bmT  = (u64*)(ws + 4 * MB);                  // 2 MB, transposed [jw][i]
    float*  s    = (float*)(ws + 6 * MB);                // 128 KB
    float*  t32  = (float*)(ws + 6 * MB + 128 * 1024);   // 128 KB
    ushort* xh   = (ushort*)(ws + 7 * MB);               // 4 MB
    ushort* xl   = (ushort*)(ws + 11 * MB);              // 4 MB
    ushort* WTs  = (ushort*)(ws + 15 * MB);              // 1 MB

    k_prep<<<dim3(65536 + 2048 + 128), dim3(256), 0, stream>>>(adj, x, W, bmT, xh, xl, WTs);
    k_proj<<<dim3(NN / 64, HH), dim3(1024), 0, stream>>>(xh, xl, WTs, a_src, a_dst, WhbT, s, t32);
    k_agg<<<dim3(NN / 64, HH), dim3(512), 0, stream>>>(WhbT, s, t32, bmT, out);
}

// Round 12
// 89.282 us; speedup vs baseline: 1.0259x; 1.0259x over previous
//
#include <hip/hip_runtime.h>
#include <hip/hip_bf16.h>
#include <math.h>

#define NN 4096
#define FIN 512
#define HH 8
#define DD 64

typedef unsigned long long u64;
typedef unsigned int u32;
typedef float f32x2 __attribute__((ext_vector_type(2)));
typedef float f32x4 __attribute__((ext_vector_type(4)));
typedef float f32x16 __attribute__((ext_vector_type(16)));
typedef short short8 __attribute__((ext_vector_type(8)));

#define GLOAD_LDS16(g, l)                                                              \
  __builtin_amdgcn_global_load_lds((const __attribute__((address_space(1))) u32*)(g),  \
                                   (__attribute__((address_space(3))) u32*)(l), 16, 0, 0)

#if __has_builtin(__builtin_amdgcn_exp2f)
#define EXP2F(x) __builtin_amdgcn_exp2f(x)
#else
#define EXP2F(x) exp2f(x)
#endif

__device__ inline ushort bf16rne(float f) {
    u32 u = __float_as_uint(f);
    u += 0x7FFFu + ((u >> 16) & 1u);
    return (ushort)(u >> 16);
}
__device__ inline float bf16tof(ushort h) {
    return __uint_as_float(((u32)h) << 16);
}

// ---------- Kernel 1: merged prep: bitpack adj (transposed) | split x | W tiles ----------
__global__ __launch_bounds__(256) void k_prep(const int* __restrict__ adj,
                                              const float* __restrict__ x,
                                              const float* __restrict__ W,
                                              u64* __restrict__ bmT,
                                              ushort* __restrict__ xh,
                                              ushort* __restrict__ xl,
                                              ushort* __restrict__ WTs) {
    int b = blockIdx.x;
    if (b < 65536) {
        int tid = b * 256 + threadIdx.x;
        int lane = threadIdx.x & 63;
        int v = adj[tid];
        u64 m = __ballot(v > 0);
        if (lane == 0) {
            int i = tid >> 12;           // row
            int j = tid & 4095;          // col of this wave's first lane
            bmT[(size_t)(j >> 6) * NN + i] = m;   // transposed: [jword][i]
        }
    } else if (b < 65536 + 2048) {
        int tid = (b - 65536) * 256 + threadIdx.x;     // NN*FIN/4 threads
        float4 v = *(const float4*)(x + (size_t)tid * 4);
        float fa[4] = {v.x, v.y, v.z, v.w};
        ushort4 hh, ll;
        ushort* hp = (ushort*)&hh; ushort* lp = (ushort*)&ll;
        #pragma unroll
        for (int k = 0; k < 4; ++k) {
            ushort hv = bf16rne(fa[k]);
            hp[k] = hv;
            lp[k] = bf16rne(fa[k] - bf16tof(hv));
        }
        *(ushort4*)(xh + (size_t)tid * 4) = hh;
        *(ushort4*)(xl + (size_t)tid * 4) = ll;
    } else {
        int gid = (b - 67584) * 256 + threadIdx.x;     // 32768 threads
        int d = gid & 63, kg = (gid >> 6) & 7, kt = (gid >> 9) & 7, h = gid >> 12;
        ushort hh[8], ll[8];
        #pragma unroll
        for (int e = 0; e < 8; ++e) {
            int f = kt * 64 + kg * 8 + e;
            float wv = W[((size_t)h * FIN + f) * DD + d];
            ushort hv = bf16rne(wv);
            hh[e] = hv;
            ll[e] = bf16rne(wv - bf16tof(hv));
        }
        *(uint4*)(WTs + ((size_t)((h * 2 + 0) * 8 + kt)) * 4096 + d * 64 + kg * 8) = *(uint4*)hh;
        *(uint4*)(WTs + ((size_t)((h * 2 + 1) * 8 + kt)) * 4096 + d * 64 + kg * 8) = *(uint4*)ll;
    }
}

// ---------- Kernel 2: MFMA projection, LDS-staged, 16 waves/block ----------
// grid (NN/64, HH), 1024 thr. Outputs WhbT linear tiles [h][it][d(64)][j(64)] bf16;
// s, t32 (both f32, pre-scaled by log2e).
__global__ __launch_bounds__(1024) void k_proj(const ushort* __restrict__ xh,
                                               const ushort* __restrict__ xl,
                                               const ushort* __restrict__ WTs,
                                               const float* __restrict__ a_src,
                                               const float* __restrict__ a_dst,
                                               ushort* __restrict__ WhbT,
                                               float* __restrict__ s,
                                               float* __restrict__ t32) {
    __shared__ ushort P[16384];        // 4 bufs (Ah,Al,Bh,Bl) x 8KB, swizzled image
    __shared__ float SP[64][5], TP[64][5];
    int h = blockIdx.y, it = blockIdx.x;
    int i0 = it * 64;
    int tid = threadIdx.x;
    int w = tid >> 6, lane = tid & 63, lm = lane & 15, g = lane >> 4;
    int w_c = w & 3, w_i = w >> 2;
    f32x4 acc = {};
    int da = w_c * 16 + lm, ib = w_i * 16 + lm;
    for (int kt = 0; kt < 8; ++kt) {
        #pragma unroll
        for (int sub = 0; sub < 2; ++sub) {
            int buf = sub * 2 + (w >> 3);          // wave-uniform
            int y0 = (w & 7) * 64;                 // wave-uniform chunk base
            int y = y0 + lane;
            int r = y >> 3;
            int cc = (y & 7) ^ (r & 7);            // sigma: inverse-swizzle source
            const ushort* src;
            if (buf == 0)      src = WTs + ((size_t)((h * 2 + 0) * 8 + kt)) * 4096 + r * 64 + cc * 8;
            else if (buf == 1) src = WTs + ((size_t)((h * 2 + 1) * 8 + kt)) * 4096 + r * 64 + cc * 8;
            else if (buf == 2) src = xh + (size_t)(i0 + r) * FIN + kt * 64 + cc * 8;
            else               src = xl + (size_t)(i0 + r) * FIN + kt * 64 + cc * 8;
            GLOAD_LDS16(src, P + buf * 4096 + y0 * 8);
        }
        __syncthreads();
        #pragma unroll
        for (int ks = 0; ks < 2; ++ks) {
            u32 offA = ((u32)(da * 128 + ks * 64 + g * 16)) ^ ((u32)(da & 7) << 4);
            u32 offB = ((u32)(ib * 128 + ks * 64 + g * 16)) ^ ((u32)(ib & 7) << 4);
            short8 ah = *(const short8*)((const char*)P + offA);
            short8 al = *(const short8*)((const char*)P + 8192 + offA);
            short8 bh = *(const short8*)((const char*)P + 16384 + offB);
            short8 bl = *(const short8*)((const char*)P + 24576 + offB);
            acc = __builtin_amdgcn_mfma_f32_16x16x32_bf16(ah, bh, acc, 0, 0, 0);
            acc = __builtin_amdgcn_mfma_f32_16x16x32_bf16(al, bh, acc, 0, 0, 0);
            acc = __builtin_amdgcn_mfma_f32_16x16x32_bf16(ah, bl, acc, 0, 0, 0);
        }
        __syncthreads();
    }
    // epilogue: s,t partials + C tile. C[row=d=w_c*16+g*4+reg][col=i=w_i*16+lm]
    float4 as4 = *(const float4*)(a_src + h * DD + w_c * 16 + g * 4);
    float4 ad4 = *(const float4*)(a_dst + h * DD + w_c * 16 + g * 4);
    float sp = acc[0] * as4.x + acc[1] * as4.y + acc[2] * as4.z + acc[3] * as4.w;
    float tp = acc[0] * ad4.x + acc[1] * ad4.y + acc[2] * ad4.z + acc[3] * ad4.w;
    sp += __shfl_xor(sp, 16); sp += __shfl_xor(sp, 32);
    tp += __shfl_xor(tp, 16); tp += __shfl_xor(tp, 32);
    if (lane < 16) { SP[w_i * 16 + lm][w_c] = sp; TP[w_i * 16 + lm][w_c] = tp; }
    #pragma unroll
    for (int reg = 0; reg < 4; ++reg) {
        int d = w_c * 16 + g * 4 + reg;
        P[d * 64 + w_i * 16 + lm] = bf16rne(acc[reg]);
    }
    __syncthreads();
    const float LOG2E = 1.4426950408889634f;
    if (tid < 64) {
        int i = i0 + tid;
        s[h * NN + i]   = (SP[tid][0] + SP[tid][1] + SP[tid][2] + SP[tid][3]) * LOG2E;
        t32[h * NN + i] = (TP[tid][0] + TP[tid][1] + TP[tid][2] + TP[tid][3]) * LOG2E;
    }
    ushort* tbase = WhbT + ((size_t)(h * 64 + it)) * 4096;
    if (tid < 512) {
        uint4 v = *(const uint4*)(P + tid * 8);
        *(uint4*)(tbase + tid * 8) = v;
    }
}

// ---------- Kernel 3: FUSED masked-softmax aggregation + ELU (r10 structure, lean body) ----------
// grid (NN/64, HH), 512 thr = 4 j-groups x 2 waves x 32 rows; full j in-block.
// LDS-staged V (gload_lds, dbuf, 1 barrier/tile), f32 t in LDS, in-LDS combine.
// Weight pair: z=s+t (pk); lrelu (pk mul + max); exp2; mask as (float)bit pk-mul;
// lacc pk-add; v_cvt_pk_bf16_f32 pack.
__global__ __launch_bounds__(512, 4) void k_agg(const ushort* __restrict__ WhbT,
                                                const float* __restrict__ s,
                                                const float* __restrict__ t32,
                                                const u64* __restrict__ bmT,
                                                float* __restrict__ out) {
    __shared__ __attribute__((aligned(16))) char SM[81920];
    ushort* Vt  = (ushort*)SM;                 // 64KB: group g at g*16384, buf p at +p*8192
    float*  tls = (float*)(SM + 65536);        // 16KB f32 t (log2-scaled), whole j-range
    float*  PL  = (float*)(SM + 65536);        // reused for l-partials after loop (t dead)
    int h = blockIdx.y;
    int i0 = blockIdx.x * 64;
    int tid = threadIdx.x;
    int w = tid >> 6, lane = tid & 63, r = lane & 31, hi = lane >> 5;
    int g = w >> 1, wr = w & 1;
    int irow = i0 + wr * 32 + r;
    float s_i = s[(size_t)h * NN + irow];      // log2-scaled
    f32x2 s2; s2[0] = s_i; s2[1] = s_i;
    // stage t once (whole head row, 16KB f32)
    {
        const float4* src = (const float4*)(t32 + (size_t)h * NN) + tid * 2;
        ((float4*)tls)[tid * 2]     = src[0];
        ((float4*)tls)[tid * 2 + 1] = src[1];
    }
    f32x16 acc0 = {}, acc1 = {};
    f32x2 lacc2 = {};
    int jtbase = g * 16;
    auto stage = [&](int p, int k) {
        const ushort* tb = WhbT + ((size_t)(h * 64 + jtbase + k)) * 4096;
        #pragma unroll
        for (int sub = 0; sub < 4; ++sub) {
            int y0 = wr * 256 + sub * 64;          // wave-uniform chunk base
            int y = y0 + lane;
            int sy = y ^ ((y >> 3) & 7);           // sigma source chunk
            GLOAD_LDS16(tb + sy * 8, (char*)Vt + g * 16384 + p * 8192 + y0 * 16);
        }
    };
    stage(0, 0);
    u64 bits = bmT[(size_t)jtbase * NN + irow];
    #pragma unroll 2
    for (int k = 0; k < 16; ++k) {
        __syncthreads();                 // buf[k&1] DMA complete; t staged; prev reads done
        if (k + 1 < 16) stage((k + 1) & 1, k + 1);
        u64 bnext = (k + 1 < 16) ? bmT[(size_t)(jtbase + k + 1) * NN + irow] : 0;
        int j0 = (jtbase + k) * 64;
        #pragma unroll
        for (int jq = 0; jq < 4; ++jq) {
            const float* tp = tls + j0 + jq * 16 + hi * 8;
            float ta[8];
            *(f32x4*)&ta[0] = *(const f32x4*)tp;
            *(f32x4*)&ta[4] = *(const f32x4*)(tp + 4);
            u32 msk = (u32)(bits >> (jq * 16 + hi * 8)) & 0xffu;
            union { u32 u[4]; short8 v8; } au;
            #pragma unroll
            for (int q = 0; q < 4; ++q) {
                f32x2 t2; t2[0] = ta[2 * q]; t2[1] = ta[2 * q + 1];
                f32x2 z  = s2 + t2;               // v_pk_add_f32
                f32x2 zl = z * 0.2f;              // v_pk_mul_f32
                float z0 = fmaxf(z[0], zl[0]);
                float z1 = fmaxf(z[1], zl[1]);
                float e0 = EXP2F(z0), e1 = EXP2F(z1);
                f32x2 m;                          // mask as arithmetic (exact 0/1)
                m[0] = (float)((msk >> (2 * q)) & 1u);
                m[1] = (float)((msk >> (2 * q + 1)) & 1u);
                f32x2 ww; ww[0] = e0; ww[1] = e1;
                ww *= m;                          // v_pk_mul_f32
                lacc2 += ww;                      // v_pk_add_f32
                u32 d;
                asm("v_cvt_pk_bf16_f32 %0, %1, %2" : "=v"(d) : "v"(ww[0]), "v"(ww[1]));
                au.u[q] = d;
            }
            u32 o0 = (u32)(g * 16384 + (k & 1) * 8192) + (u32)(r * 128) +
                     (((u32)(jq * 32 + hi * 16)) ^ ((u32)(r & 7) << 4));
            short8 b0 = *(const short8*)((const char*)Vt + o0);
            short8 b1 = *(const short8*)((const char*)Vt + o0 + 4096);
            __builtin_amdgcn_s_setprio(1);
            acc0 = __builtin_amdgcn_mfma_f32_32x32x16_bf16(au.v8, b0, acc0, 0, 0, 0);
            acc1 = __builtin_amdgcn_mfma_f32_32x32x16_bf16(au.v8, b1, acc1, 0, 0, 0);
            __builtin_amdgcn_s_setprio(0);
        }
        bits = bnext;
    }
    // ---- in-block combine ----
    float lacc = lacc2[0] + lacc2[1];
    lacc += __shfl_xor(lacc, 32);
    __syncthreads();                     // all waves done reading Vt & tls
    float* PTg = (float*)(SM + g * 16384);   // [64 rows][64 d] per group (over Vt)
    #pragma unroll
    for (int reg = 0; reg < 16; ++reg) {
        int rowl = (reg & 3) + 8 * (reg >> 2) + 4 * hi;
        PTg[(wr * 32 + rowl) * 64 + r]      = acc0[reg];
        PTg[(wr * 32 + rowl) * 64 + 32 + r] = acc1[reg];
    }
    if (lane < 32) PL[g * 64 + wr * 32 + lane] = lacc;
    __syncthreads();
    // epilogue: tid -> row (0..63), d0 = 8-float group
    int row = tid >> 3, d0 = (tid & 7) * 8;
    f32x4 a0 = {}, a1 = {};
    float l = 0.f;
    #pragma unroll
    for (int gg = 0; gg < 4; ++gg) {
        const float* Pp = (const float*)(SM + gg * 16384) + row * 64 + d0;
        a0 += *(const f32x4*)Pp;
        a1 += *(const f32x4*)(Pp + 4);
        l += PL[gg * 64 + row];
    }
    float inv = 1.f / l;
    float o[8];
    #pragma unroll
    for (int dd = 0; dd < 4; ++dd) {
        float u0 = a0[dd] * inv;
        float u1 = a1[dd] * inv;
        o[dd]     = u0 > 0.f ? u0 : __expf(u0) - 1.f;
        o[dd + 4] = u1 > 0.f ? u1 : __expf(u1) - 1.f;
    }
    float* ob = out + (size_t)(i0 + row) * (HH * DD) + h * DD + d0;
    *(float4*)ob       = make_float4(o[0], o[1], o[2], o[3]);
    *(float4*)(ob + 4) = make_float4(o[4], o[5], o[6], o[7]);
}

extern "C" void kernel_launch(void* const* d_in, const int* in_sizes, int n_in,
                              void* d_out, int out_size, void* d_ws, size_t ws_size,
                              hipStream_t stream) {
    const float* x     = (const float*)d_in[0];
    const int*   adj   = (const int*)d_in[1];
    const float* W     = (const float*)d_in[2];
    const float* a_src = (const float*)d_in[3];
    const float* a_dst = (const float*)d_in[4];
    float* out = (float*)d_out;

    char* ws = (char*)d_ws;
    const size_t MB = 1024 * 1024;
    ushort* WhbT = (ushort*)ws;                          // 4 MB, linear tiles
    u64*    bmT  = (u64*)(ws + 4 * MB);                  // 2 MB, transposed [jw][i]
    float*  s    = (float*)(ws + 6 * MB);                // 128 KB
    float*  t32  = (float*)(ws + 6 * MB + 128 * 1024);   // 128 KB
    ushort* xh   = (ushort*)(ws + 7 * MB);               // 4 MB
    ushort* xl   = (ushort*)(ws + 11 * MB);              // 4 MB
    ushort* WTs  = (ushort*)(ws + 15 * MB);              // 1 MB

    k_prep<<<dim3(65536 + 2048 + 128), dim3(256), 0, stream>>>(adj, x, W, bmT, xh, xl, WTs);
    k_proj<<<dim3(NN / 64, HH), dim3(1024), 0, stream>>>(xh, xl, WTs, a_src, a_dst, WhbT, s, t32);
    k_agg<<<dim3(NN / 64, HH), dim3(512), 0, stream>>>(WhbT, s, t32, bmT, out);
}

// Round 13
// 87.403 us; speedup vs baseline: 1.0479x; 1.0215x over previous
//
#include <hip/hip_runtime.h>
#include <hip/hip_bf16.h>
#include <math.h>

#define NN 4096
#define FIN 512
#define HH 8
#define DD 64

typedef unsigned long long u64;
typedef unsigned int u32;
typedef float f32x2 __attribute__((ext_vector_type(2)));
typedef float f32x4 __attribute__((ext_vector_type(4)));
typedef float f32x16 __attribute__((ext_vector_type(16)));
typedef short short8 __attribute__((ext_vector_type(8)));

#define GLOAD_LDS16(g, l)                                                              \
  __builtin_amdgcn_global_load_lds((const __attribute__((address_space(1))) u32*)(g),  \
                                   (__attribute__((address_space(3))) u32*)(l), 16, 0, 0)

#if __has_builtin(__builtin_amdgcn_exp2f)
#define EXP2F(x) __builtin_amdgcn_exp2f(x)
#else
#define EXP2F(x) exp2f(x)
#endif

__device__ inline ushort bf16rne(float f) {
    u32 u = __float_as_uint(f);
    u += 0x7FFFu + ((u >> 16) & 1u);
    return (ushort)(u >> 16);
}
__device__ inline float bf16tof(ushort h) {
    return __uint_as_float(((u32)h) << 16);
}

// ---------- Kernel 1: x split hi/lo + W tiles (small, HBM-light) ----------
// blocks [0,2048): prepx; [2048,2176): prepw.
__global__ __launch_bounds__(256) void k_prep2(const float* __restrict__ x,
                                               const float* __restrict__ W,
                                               ushort* __restrict__ xh,
                                               ushort* __restrict__ xl,
                                               ushort* __restrict__ WTs) {
    int b = blockIdx.x;
    if (b < 2048) {
        int tid = b * 256 + threadIdx.x;               // NN*FIN/4 threads
        float4 v = *(const float4*)(x + (size_t)tid * 4);
        float fa[4] = {v.x, v.y, v.z, v.w};
        ushort4 hh, ll;
        ushort* hp = (ushort*)&hh; ushort* lp = (ushort*)&ll;
        #pragma unroll
        for (int k = 0; k < 4; ++k) {
            ushort hv = bf16rne(fa[k]);
            hp[k] = hv;
            lp[k] = bf16rne(fa[k] - bf16tof(hv));
        }
        *(ushort4*)(xh + (size_t)tid * 4) = hh;
        *(ushort4*)(xl + (size_t)tid * 4) = ll;
    } else {
        int gid = (b - 2048) * 256 + threadIdx.x;      // 32768 threads
        int d = gid & 63, kg = (gid >> 6) & 7, kt = (gid >> 9) & 7, h = gid >> 12;
        ushort hh[8], ll[8];
        #pragma unroll
        for (int e = 0; e < 8; ++e) {
            int f = kt * 64 + kg * 8 + e;
            float wv = W[((size_t)h * FIN + f) * DD + d];
            ushort hv = bf16rne(wv);
            hh[e] = hv;
            ll[e] = bf16rne(wv - bf16tof(hv));
        }
        *(uint4*)(WTs + ((size_t)((h * 2 + 0) * 8 + kt)) * 4096 + d * 64 + kg * 8) = *(uint4*)hh;
        *(uint4*)(WTs + ((size_t)((h * 2 + 1) * 8 + kt)) * 4096 + d * 64 + kg * 8) = *(uint4*)ll;
    }
}

// ---------- Kernel 2: FUSED proj (blocks 0-511) + adj bitpack (blocks 512-16895) ----------
// Proj: MFMA/LDS-bound, HBM-light. Bitpack: pure HBM (64MB adj). Disjoint pipes ->
// co-scheduled blocks overlap instead of serializing two launches.
__global__ __launch_bounds__(1024) void k_projbp(const ushort* __restrict__ xh,
                                                 const ushort* __restrict__ xl,
                                                 const ushort* __restrict__ WTs,
                                                 const float* __restrict__ a_src,
                                                 const float* __restrict__ a_dst,
                                                 const int* __restrict__ adj,
                                                 ushort* __restrict__ WhbT,
                                                 float* __restrict__ s,
                                                 float* __restrict__ t32,
                                                 u64* __restrict__ bmT) {
    if (blockIdx.x >= 512) {
        // ---- bitpack: 16384 blocks x 1024 threads, 1 adj element each ----
        int idx = (blockIdx.x - 512) * 1024 + threadIdx.x;
        int v = adj[idx];
        u64 m = __ballot(v > 0);
        if ((threadIdx.x & 63) == 0) {
            int i = idx >> 12;               // row
            int j = idx & 4095;              // col of wave's first lane
            bmT[(size_t)(j >> 6) * NN + i] = m;   // transposed: [jword][i]
        }
        return;
    }
    // ---- proj: h = b>>6, it = b&63 ----
    __shared__ ushort P[16384];        // 4 bufs (Ah,Al,Bh,Bl) x 8KB, swizzled image
    __shared__ float SP[64][5], TP[64][5];
    int h = blockIdx.x >> 6, it = blockIdx.x & 63;
    int i0 = it * 64;
    int tid = threadIdx.x;
    int w = tid >> 6, lane = tid & 63, lm = lane & 15, g = lane >> 4;
    int w_c = w & 3, w_i = w >> 2;
    f32x4 acc = {};
    int da = w_c * 16 + lm, ib = w_i * 16 + lm;
    for (int kt = 0; kt < 8; ++kt) {
        #pragma unroll
        for (int sub = 0; sub < 2; ++sub) {
            int buf = sub * 2 + (w >> 3);          // wave-uniform
            int y0 = (w & 7) * 64;                 // wave-uniform chunk base
            int y = y0 + lane;
            int r = y >> 3;
            int cc = (y & 7) ^ (r & 7);            // sigma: inverse-swizzle source
            const ushort* src;
            if (buf == 0)      src = WTs + ((size_t)((h * 2 + 0) * 8 + kt)) * 4096 + r * 64 + cc * 8;
            else if (buf == 1) src = WTs + ((size_t)((h * 2 + 1) * 8 + kt)) * 4096 + r * 64 + cc * 8;
            else if (buf == 2) src = xh + (size_t)(i0 + r) * FIN + kt * 64 + cc * 8;
            else               src = xl + (size_t)(i0 + r) * FIN + kt * 64 + cc * 8;
            GLOAD_LDS16(src, P + buf * 4096 + y0 * 8);
        }
        __syncthreads();
        #pragma unroll
        for (int ks = 0; ks < 2; ++ks) {
            u32 offA = ((u32)(da * 128 + ks * 64 + g * 16)) ^ ((u32)(da & 7) << 4);
            u32 offB = ((u32)(ib * 128 + ks * 64 + g * 16)) ^ ((u32)(ib & 7) << 4);
            short8 ah = *(const short8*)((const char*)P + offA);
            short8 al = *(const short8*)((const char*)P + 8192 + offA);
            short8 bh = *(const short8*)((const char*)P + 16384 + offB);
            short8 bl = *(const short8*)((const char*)P + 24576 + offB);
            acc = __builtin_amdgcn_mfma_f32_16x16x32_bf16(ah, bh, acc, 0, 0, 0);
            acc = __builtin_amdgcn_mfma_f32_16x16x32_bf16(al, bh, acc, 0, 0, 0);
            acc = __builtin_amdgcn_mfma_f32_16x16x32_bf16(ah, bl, acc, 0, 0, 0);
        }
        __syncthreads();
    }
    // epilogue: s,t partials + C tile. C[row=d=w_c*16+g*4+reg][col=i=w_i*16+lm]
    float4 as4 = *(const float4*)(a_src + h * DD + w_c * 16 + g * 4);
    float4 ad4 = *(const float4*)(a_dst + h * DD + w_c * 16 + g * 4);
    float sp = acc[0] * as4.x + acc[1] * as4.y + acc[2] * as4.z + acc[3] * as4.w;
    float tp = acc[0] * ad4.x + acc[1] * ad4.y + acc[2] * ad4.z + acc[3] * ad4.w;
    sp += __shfl_xor(sp, 16); sp += __shfl_xor(sp, 32);
    tp += __shfl_xor(tp, 16); tp += __shfl_xor(tp, 32);
    if (lane < 16) { SP[w_i * 16 + lm][w_c] = sp; TP[w_i * 16 + lm][w_c] = tp; }
    #pragma unroll
    for (int reg = 0; reg < 4; ++reg) {
        int d = w_c * 16 + g * 4 + reg;
        P[d * 64 + w_i * 16 + lm] = bf16rne(acc[reg]);
    }
    __syncthreads();
    const float LOG2E = 1.4426950408889634f;
    if (tid < 64) {
        int i = i0 + tid;
        s[h * NN + i]   = (SP[tid][0] + SP[tid][1] + SP[tid][2] + SP[tid][3]) * LOG2E;
        t32[h * NN + i] = (TP[tid][0] + TP[tid][1] + TP[tid][2] + TP[tid][3]) * LOG2E;
    }
    ushort* tbase = WhbT + ((size_t)(h * 64 + it)) * 4096;
    if (tid < 512) {
        uint4 v = *(const uint4*)(P + tid * 8);
        *(uint4*)(tbase + tid * 8) = v;
    }
}

// ---------- Kernel 3: FUSED masked-softmax aggregation + ELU (r10 best, verbatim) ----------
// grid (NN/64, HH), 512 thr = 4 j-groups x 2 waves x 32 rows; full j in-block.
// LDS-staged V (gload_lds, dbuf, 1 barrier/tile), f32 t in LDS, in-LDS combine.
__global__ __launch_bounds__(512, 4) void k_agg(const ushort* __restrict__ WhbT,
                                                const float* __restrict__ s,
                                                const float* __restrict__ t32,
                                                const u64* __restrict__ bmT,
                                                float* __restrict__ out) {
    __shared__ __attribute__((aligned(16))) char SM[81920];
    ushort* Vt  = (ushort*)SM;                 // 64KB: group g at g*16384, buf p at +p*8192
    float*  tls = (float*)(SM + 65536);        // 16KB f32 t (log2-scaled), whole j-range
    float*  PL  = (float*)(SM + 65536);        // reused for l-partials after loop (t dead)
    int h = blockIdx.y;
    int i0 = blockIdx.x * 64;
    int tid = threadIdx.x;
    int w = tid >> 6, lane = tid & 63, r = lane & 31, hi = lane >> 5;
    int g = w >> 1, wr = w & 1;
    int irow = i0 + wr * 32 + r;
    float s_i = s[(size_t)h * NN + irow];      // log2-scaled
    f32x2 s2; s2[0] = s_i; s2[1] = s_i;
    // stage t once (whole head row, 16KB f32)
    {
        const float4* src = (const float4*)(t32 + (size_t)h * NN) + tid * 2;
        ((float4*)tls)[tid * 2]     = src[0];
        ((float4*)tls)[tid * 2 + 1] = src[1];
    }
    f32x16 acc0 = {}, acc1 = {};
    float lacc = 0.f;
    int jtbase = g * 16;
    auto stage = [&](int p, int k) {
        const ushort* tb = WhbT + ((size_t)(h * 64 + jtbase + k)) * 4096;
        #pragma unroll
        for (int sub = 0; sub < 4; ++sub) {
            int y0 = wr * 256 + sub * 64;          // wave-uniform chunk base
            int y = y0 + lane;
            int sy = y ^ ((y >> 3) & 7);           // sigma source chunk
            GLOAD_LDS16(tb + sy * 8, (char*)Vt + g * 16384 + p * 8192 + y0 * 16);
        }
    };
    stage(0, 0);
    u64 bits = bmT[(size_t)jtbase * NN + irow];
    #pragma unroll 2
    for (int k = 0; k < 16; ++k) {
        __syncthreads();                 // buf[k&1] DMA complete; t staged; prev reads done
        if (k + 1 < 16) stage((k + 1) & 1, k + 1);
        u64 bnext = (k + 1 < 16) ? bmT[(size_t)(jtbase + k + 1) * NN + irow] : 0;
        int j0 = (jtbase + k) * 64;
        #pragma unroll
        for (int jq = 0; jq < 4; ++jq) {
            const float* tp = tls + j0 + jq * 16 + hi * 8;
            float ta[8];
            *(f32x4*)&ta[0] = *(const f32x4*)tp;
            *(f32x4*)&ta[4] = *(const f32x4*)(tp + 4);
            u32 msk = (u32)(bits >> (jq * 16 + hi * 8)) & 0xffu;
            union { u32 u[4]; short8 v8; } au;
            #pragma unroll
            for (int q = 0; q < 4; ++q) {
                f32x2 t2; t2[0] = ta[2 * q]; t2[1] = ta[2 * q + 1];
                f32x2 z = s2 + t2;               // v_pk_add_f32
                f32x2 zl = z * 0.2f;             // v_pk_mul_f32
                float z0 = fmaxf(z[0], zl[0]);
                float z1 = fmaxf(z[1], zl[1]);
                float e0 = EXP2F(z0), e1 = EXP2F(z1);
                e0 = ((msk >> (2 * q)) & 1u) ? e0 : 0.f;
                e1 = ((msk >> (2 * q + 1)) & 1u) ? e1 : 0.f;
                lacc += e0 + e1;
                __hip_bfloat162 b2 = __float22bfloat162_rn(make_float2(e0, e1));
                au.u[q] = *(u32*)&b2;
            }
            u32 o0 = (u32)(g * 16384 + (k & 1) * 8192) + (u32)(r * 128) +
                     (((u32)(jq * 32 + hi * 16)) ^ ((u32)(r & 7) << 4));
            short8 b0 = *(const short8*)((const char*)Vt + o0);
            short8 b1 = *(const short8*)((const char*)Vt + o0 + 4096);
            __builtin_amdgcn_s_setprio(1);
            acc0 = __builtin_amdgcn_mfma_f32_32x32x16_bf16(au.v8, b0, acc0, 0, 0, 0);
            acc1 = __builtin_amdgcn_mfma_f32_32x32x16_bf16(au.v8, b1, acc1, 0, 0, 0);
            __builtin_amdgcn_s_setprio(0);
        }
        bits = bnext;
    }
    // ---- in-block combine ----
    lacc += __shfl_xor(lacc, 32);
    __syncthreads();                     // all waves done reading Vt & tls
    float* PTg = (float*)(SM + g * 16384);   // [64 rows][64 d] per group (over Vt)
    #pragma unroll
    for (int reg = 0; reg < 16; ++reg) {
        int rowl = (reg & 3) + 8 * (reg >> 2) + 4 * hi;
        PTg[(wr * 32 + rowl) * 64 + r]      = acc0[reg];
        PTg[(wr * 32 + rowl) * 64 + 32 + r] = acc1[reg];
    }
    if (lane < 32) PL[g * 64 + wr * 32 + lane] = lacc;
    __syncthreads();
    // epilogue: tid -> row (0..63), d0 = 8-float group
    int row = tid >> 3, d0 = (tid & 7) * 8;
    f32x4 a0 = {}, a1 = {};
    float l = 0.f;
    #pragma unroll
    for (int gg = 0; gg < 4; ++gg) {
        const float* Pp = (const float*)(SM + gg * 16384) + row * 64 + d0;
        a0 += *(const f32x4*)Pp;
        a1 += *(const f32x4*)(Pp + 4);
        l += PL[gg * 64 + row];
    }
    float inv = 1.f / l;
    float o[8];
    #pragma unroll
    for (int dd = 0; dd < 4; ++dd) {
        float u0 = a0[dd] * inv;
        float u1 = a1[dd] * inv;
        o[dd]     = u0 > 0.f ? u0 : __expf(u0) - 1.f;
        o[dd + 4] = u1 > 0.f ? u1 : __expf(u1) - 1.f;
    }
    float* ob = out + (size_t)(i0 + row) * (HH * DD) + h * DD + d0;
    *(float4*)ob       = make_float4(o[0], o[1], o[2], o[3]);
    *(float4*)(ob + 4) = make_float4(o[4], o[5], o[6], o[7]);
}

extern "C" void kernel_launch(void* const* d_in, const int* in_sizes, int n_in,
                              void* d_out, int out_size, void* d_ws, size_t ws_size,
                              hipStream_t stream) {
    const float* x     = (const float*)d_in[0];
    const int*   adj   = (const int*)d_in[1];
    const float* W     = (const float*)d_in[2];
    const float* a_src = (const float*)d_in[3];
    const float* a_dst = (const float*)d_in[4];
    float* out = (float*)d_out;

    char* ws = (char*)d_ws;
    const size_t MB = 1024 * 1024;
    ushort* WhbT = (ushort*)ws;                          // 4 MB, linear tiles
    u64*    bmT  = (u64*)(ws + 4 * MB);                  // 2 MB, transposed [jw][i]
    float*  s    = (float*)(ws + 6 * MB);                // 128 KB
    float*  t32  = (float*)(ws + 6 * MB + 128 * 1024);   // 128 KB
    ushort* xh   = (ushort*)(ws + 7 * MB);               // 4 MB
    ushort* xl   = (ushort*)(ws + 11 * MB);              // 4 MB
    ushort* WTs  = (ushort*)(ws + 15 * MB);              // 1 MB

    k_prep2<<<dim3(2048 + 128), dim3(256), 0, stream>>>(x, W, xh, xl, WTs);
    k_projbp<<<dim3(512 + 16384), dim3(1024), 0, stream>>>(xh, xl, WTs, a_src, a_dst,
                                                           adj, WhbT, s, t32, bmT);
    k_agg<<<dim3(NN / 64, HH), dim3(512), 0, stream>>>(WhbT, s, t32, bmT, out);
}